// Round 14
// baseline (309.103 us; speedup 1.0000x reference)
//
#include <hip/hip_runtime.h>
#include <cstddef>

// ButterFlyNet2D IDFT forward. Split-bf16 MFMA (3-pass: Whi*Yhi + Whi*Ylo + Wlo*Yhi).
// Activations: ONE u32 per element = packed (hi bf16 | lo bf16<<16).
//   Plane layout A[gy][gx][i][k][l][b][p][q] -> per block contiguous Y[256][Nb].
// R14 = R13 with rec1-3 moved to NT=64 + __launch_bounds__(256,3): accumulator
// halves (128->64 VGPR) so 3 wgs/CU fit -> 12 waves/CU of cross-wg overlap to
// hide the 2-phase barrier stalls (m114/m97 occupancy regime). W re-reads双 are
// L2/L3-absorbed. rec45 + layer0 byte-identical to R13.

typedef unsigned int  u32;
typedef unsigned short u16;
typedef __attribute__((ext_vector_type(8))) short bf16x8;
typedef __attribute__((ext_vector_type(4))) float f32x4;

#define PLANE 16777216   // elements per activation buffer

__device__ inline float bf16_to_f(u16 h) {
    u32 u = ((u32)h) << 16;
    return __builtin_bit_cast(float, u);
}
// Truncation-split pack: hi = bit-trunc(x) (top16), lo = trunc_bf16(x - hi).
// x - hi is exact in f32; |x - (hi+lo)| <= 2^-16 |x|. ~4 VALU ops.
__device__ inline u32 pack_trunc(float v) {
    const u32 u = __builtin_bit_cast(u32, v);
    const float hi = __builtin_bit_cast(float, u & 0xFFFF0000u);
    const u32 lo = __builtin_bit_cast(u32, v - hi);
    return (u >> 16) | (lo & 0xFFFF0000u);
}
// LDS-only barrier: drains ds ops, leaves global loads (vmcnt) in flight.
__device__ inline void bar_lds() {
    asm volatile("s_waitcnt lgkmcnt(0)\n\ts_barrier" ::: "memory");
}

// ---------------- Layer 0: x read once, 128 outputs per thread ----------------
__global__ __launch_bounds__(256)
void layer0_kernel(const float* __restrict__ xr, const float* __restrict__ xi,
                   const float* __restrict__ w0, const float* __restrict__ b0,
                   u32* __restrict__ A1) {
    __shared__ float w0s[128][16];
    __shared__ float b0s[128];
    const int og  = blockIdx.y;             // 0/1: o = og*128 + j
    const int tid = threadIdx.x;
    {
        const int row = tid >> 1, half = tid & 1;
        const float4 wa = *(const float4*)(w0 + (og * 128 + row) * 16 + half * 8);
        const float4 wb = *(const float4*)(w0 + (og * 128 + row) * 16 + half * 8 + 4);
        *(float4*)&w0s[row][half * 8]     = wa;
        *(float4*)&w0s[row][half * 8 + 4] = wb;
        if (tid < 128) b0s[tid] = b0[og * 128 + tid];
    }
    __syncthreads();

    const int n = blockIdx.x * 256 + tid;   // output pixel: b*1024 + p*32 + q
    const int b = n >> 10, p = (n >> 5) & 31, q = n & 31;
    float xs[16];
#pragma unroll
    for (int k = 0; k < 2; ++k) {
        const float2 vr = *(const float2*)(xr + b * 4096 + (2 * p + k) * 64 + 2 * q);
        const float2 vi = *(const float2*)(xi + b * 4096 + (2 * p + k) * 64 + 2 * q);
        xs[0  + k * 2 + 0] = fmaxf(vr.x, 0.f);  xs[0  + k * 2 + 1] = fmaxf(vr.y, 0.f);
        xs[4  + k * 2 + 0] = fmaxf(vi.x, 0.f);  xs[4  + k * 2 + 1] = fmaxf(vi.y, 0.f);
        xs[8  + k * 2 + 0] = fmaxf(-vr.x, 0.f); xs[8  + k * 2 + 1] = fmaxf(-vr.y, 0.f);
        xs[12 + k * 2 + 0] = fmaxf(-vi.x, 0.f); xs[12 + k * 2 + 1] = fmaxf(-vi.y, 0.f);
    }
    const int kp = p & 1, lp = q & 1, pp = p >> 1, qp = q >> 1;
    const size_t pixoff = (size_t)(b * 256 + pp * 16 + qp);
#pragma unroll
    for (int j = 0; j < 128; ++j) {
        float acc = b0s[j];
#pragma unroll
        for (int e = 0; e < 16; ++e) acc = fmaf(xs[e], w0s[j][e], acc);
        acc = fmaxf(acc, 0.f);
        const int o = og * 128 + j;
        const int gy = o >> 7, gx = (o >> 6) & 1, c = o & 63;
        const size_t flat = (size_t)((((gy * 2 + gx) * 64 + c) * 2 + kp) * 2 + lp) * (64 * 256)
                          + pixoff;
        A1[flat] = pack_trunc(acc);
    }
}

// ------- Recursion layers 1..3 : split-bf16 MFMA, W f32 direct + trunc-split -------
// NT=64, 3 wgs/CU (12 waves/CU) for cross-wg barrier-stall hiding.
template<int NT>
__global__ __launch_bounds__(256, 3)
void rec_mfma_kernel(const u32* __restrict__ Yg, const float* __restrict__ Wf,
                     const float* __restrict__ bias, u32* __restrict__ Aout,
                     const int lgG, const int lgS2) {
    constexpr int NF  = NT / 16;
    constexpr int LD  = 40;
    constexpr int NCP = NT / 2;
    constexpr int RPT = 32 / (256 / NCP);

    __shared__ u16 Yhi_s[NT * LD];
    __shared__ u16 Ylo_s[NT * LD];

    const int G  = 1 << lgG;
    const int S2 = 1 << lgS2;
    const int Nb = 64 << (2 * lgS2);

    // XCD-chunked swizzle: keep all n-tiles of a block on one XCD (W L2 reuse)
    int bid, nt;
    const int nBid = G * G, NTILES = gridDim.x;
    if (nBid >= 8) {
        const int h = blockIdx.z * NTILES + blockIdx.x;
        const int xcd = h & 7, j = h >> 3, per = nBid >> 3;
        bid = xcd * per + j / NTILES;
        nt  = j % NTILES;
    } else { bid = blockIdx.z; nt = blockIdx.x; }

    const size_t wbase = (size_t)bid * 65536;
    const u32* Yblk = Yg + (size_t)bid * 256 * (size_t)Nb + (size_t)nt * NT;

    const int tid = threadIdx.x, wave = tid >> 6, lane = tid & 63;
    const int l16 = lane & 15, lk = lane >> 4;
    const int cp = tid % NCP, rg = tid / NCP;
    const int col0 = cp * 2, trow = rg * RPT;

    f32x4 acc[4][NF];
#pragma unroll
    for (int m = 0; m < 4; ++m)
#pragma unroll
        for (int n = 0; n < NF; ++n)
            acc[m][n] = (f32x4){0.f, 0.f, 0.f, 0.f};

    uint2  yreg[2][RPT];
    float4 wv[8];
    bf16x8 wh[4], wl[4];
    u32 yhw[2][RPT / 2], ylw[2][RPT / 2];

    auto loadY = [&](int ybuf, int k0) {
#pragma unroll
        for (int r = 0; r < RPT; ++r)
            yreg[ybuf][r] = *(const uint2*)(Yblk + (size_t)(k0 + trow + r) * Nb + col0);
    };
    auto loadWf32 = [&](int k0) {
#pragma unroll
        for (int m = 0; m < 4; ++m) {
            const float* p = Wf + wbase + (size_t)(wave * 64 + m * 16 + l16) * 256 + k0 + lk * 8;
            wv[2 * m]     = *(const float4*)p;
            wv[2 * m + 1] = *(const float4*)(p + 4);
        }
    };
    auto convW = [&]() {
#pragma unroll
        for (int m = 0; m < 4; ++m) {
            union { float4 f4[2]; u32 w[8]; } in;
            in.f4[0] = wv[2 * m];
            in.f4[1] = wv[2 * m + 1];
            union { u32 w[4]; bf16x8 v; } H, L;
#pragma unroll
            for (int j = 0; j < 4; ++j) {
                const u32 u0 = in.w[2 * j], u1 = in.w[2 * j + 1];
                const float x0 = __builtin_bit_cast(float, u0);
                const float x1 = __builtin_bit_cast(float, u1);
                const float h0 = __builtin_bit_cast(float, u0 & 0xFFFF0000u);
                const float h1 = __builtin_bit_cast(float, u1 & 0xFFFF0000u);
                const u32 l0 = __builtin_bit_cast(u32, x0 - h0);
                const u32 l1 = __builtin_bit_cast(u32, x1 - h1);
                H.w[j] = (u0 >> 16) | (u1 & 0xFFFF0000u);
                L.w[j] = (l0 >> 16) | (l1 & 0xFFFF0000u);
            }
            wh[m] = H.v;
            wl[m] = L.v;
        }
    };
    auto prepY = [&](int ybuf) {
#pragma unroll
        for (int c = 0; c < 2; ++c)
#pragma unroll
            for (int j2 = 0; j2 < RPT / 2; ++j2) {
                const u32 a = c ? yreg[ybuf][2 * j2].y     : yreg[ybuf][2 * j2].x;
                const u32 b = c ? yreg[ybuf][2 * j2 + 1].y : yreg[ybuf][2 * j2 + 1].x;
                yhw[c][j2] = (a & 0xFFFFu) | (b << 16);
                ylw[c][j2] = (a >> 16)     | (b & 0xFFFF0000u);
            }
    };
    auto stageY = [&]() {
#pragma unroll
        for (int c = 0; c < 2; ++c) {
            if constexpr (RPT == 8) {
                *(uint4*)&Yhi_s[(col0 + c) * LD + trow] = make_uint4(yhw[c][0], yhw[c][1], yhw[c][2], yhw[c][3]);
                *(uint4*)&Ylo_s[(col0 + c) * LD + trow] = make_uint4(ylw[c][0], ylw[c][1], ylw[c][2], ylw[c][3]);
            } else {
                *(uint2*)&Yhi_s[(col0 + c) * LD + trow] = make_uint2(yhw[c][0], yhw[c][1]);
                *(uint2*)&Ylo_s[(col0 + c) * LD + trow] = make_uint2(ylw[c][0], ylw[c][1]);
            }
        }
    };

    loadY(0, 0); loadY(1, 32);

#pragma unroll
    for (int it = 0; it < 8; ++it) {
        const int k0 = it * 32;
        const int cur = it & 1;
        loadWf32(k0);            // in flight across barriers (no vmcnt drain)
        prepY(cur);              // waits on yreg[cur] (issued 2 iters ago)
        bar_lds();               // prev MFMA ds_reads done; LDS reusable
        stageY();
        bar_lds();               // Y tile visible
        if (it + 2 < 8) loadY(cur, k0 + 64);
        convW();                 // waits on wv (issued before the barriers)
        __builtin_amdgcn_s_setprio(1);
#pragma unroll
        for (int n = 0; n < NF; ++n) {
            const int ccol = n * 16 + l16;
            const bf16x8 bhi = *(const bf16x8*)&Yhi_s[ccol * LD + 8 * lk];
            const bf16x8 blo = *(const bf16x8*)&Ylo_s[ccol * LD + 8 * lk];
#pragma unroll
            for (int m = 0; m < 4; ++m)
                acc[m][n] = __builtin_amdgcn_mfma_f32_16x16x32_bf16(wh[m], bhi, acc[m][n], 0, 0, 0);
#pragma unroll
            for (int m = 0; m < 4; ++m)
                acc[m][n] = __builtin_amdgcn_mfma_f32_16x16x32_bf16(wh[m], blo, acc[m][n], 0, 0, 0);
#pragma unroll
            for (int m = 0; m < 4; ++m)
                acc[m][n] = __builtin_amdgcn_mfma_f32_16x16x32_bf16(wl[m], bhi, acc[m][n], 0, 0, 0);
        }
        __builtin_amdgcn_s_setprio(0);
    }

    // ---- epilogue: bias + relu + packed scatter to child blocks ----
    const int gy = bid >> lgG, gx = bid & (G - 1);
    const int NS2 = S2 >> 1;
#pragma unroll
    for (int m = 0; m < 4; ++m) {
#pragma unroll
        for (int r = 0; r < 4; ++r) {
            const int oc = wave * 64 + m * 16 + lk * 4 + r;   // C/D: row=(lane>>4)*4+reg
            const float bi = bias[(size_t)bid * 256 + oc];
            const int yl = oc >> 7, xl = (oc >> 6) & 1, cch = oc & 63;
            const int cy = 2 * gy + yl, cx = 2 * gx + xl;
            const size_t base = (size_t)((cy * (2 * G) + cx) * 64 + cch);
#pragma unroll
            for (int n = 0; n < NF; ++n) {
                const float v = fmaxf(acc[m][n][r] + bi, 0.f);
                const int ng = nt * NT + n * 16 + l16;        // C/D: col=lane&15
                const int b   = ng >> (2 * lgS2);
                const int rem = ng & ((1 << (2 * lgS2)) - 1);
                const int p = rem >> lgS2, q = rem & (S2 - 1);
                const size_t flat = ((base * 2 + (p & 1)) * 2 + (q & 1)) * (size_t)(64 * NS2 * NS2)
                                  + (size_t)(b * NS2 * NS2 + (p >> 1) * NS2 + (q >> 1));
                Aout[flat] = pack_trunc(v);
            }
        }
    }
}

// ---------------- Fused L4 + L5 + final (R13 structure, unchanged) ----------------
__global__ __launch_bounds__(256, 2)
void rec45_final_kernel(const u32* __restrict__ Yg, const float* __restrict__ W4,
                        const float* __restrict__ b4, const float* __restrict__ W5,
                        const float* __restrict__ b5, const float* __restrict__ wf,
                        const float* __restrict__ bff, float* __restrict__ out) {
    constexpr int LDW = 72;                 // window row stride (u16)
    __shared__ u16 Whi_w[64 * LDW];
    __shared__ u16 Wlo_w[64 * LDW];

    const int h = blockIdx.x;
    const int parent = ((h >> 5) << 3) | (h & 7);   // 0..255 = pgy*16+pgx
    const int child  = (h >> 3) & 3;
    const int pgy = parent >> 4, pgx = parent & 15;
    const int cy = 2 * pgy + (child >> 1), cx = 2 * pgx + (child & 1);
    const int bid5 = cy * 32 + cx;
    const int ocbase = child * 64;

    const u32* Yblk  = Yg + (size_t)parent * 65536;
    const float* W4s = W4 + (size_t)parent * 65536 + (size_t)ocbase * 256;
    const float* W5b = W5 + (size_t)bid5 * 65536;

    const int tid = threadIdx.x, wave = tid >> 6, lane = tid & 63;
    const int l16 = lane & 15, lk = lane >> 4;

    f32x4 acc1[4][4];
#pragma unroll
    for (int m = 0; m < 4; ++m)
#pragma unroll
        for (int n = 0; n < 4; ++n)
            acc1[m][n] = (f32x4){0.f, 0.f, 0.f, 0.f};

    u32    yf[2][4][8];
    float4 wv[2][8];
    bf16x8 wh[4], wl[4];

    auto loadY = [&](int buf, int k0) {
#pragma unroll
        for (int n = 0; n < 4; ++n)
#pragma unroll
            for (int j = 0; j < 8; ++j)
                yf[buf][n][j] = Yblk[(size_t)(k0 + 8 * lk + j) * 256 + wave * 64 + n * 16 + l16];
    };
    auto loadW4 = [&](int buf, int k0) {
#pragma unroll
        for (int m = 0; m < 4; ++m) {
            const float* p = W4s + (size_t)(m * 16 + l16) * 256 + k0 + lk * 8;
            wv[buf][2 * m]     = *(const float4*)p;
            wv[buf][2 * m + 1] = *(const float4*)(p + 4);
        }
    };
    auto loadW5 = [&](int buf, int t) {
#pragma unroll
        for (int m = 0; m < 4; ++m) {
            const float* p = W5b + (size_t)(wave * 64 + m * 16 + l16) * 256 + t * 32 + lk * 8;
            wv[buf][2 * m]     = *(const float4*)p;
            wv[buf][2 * m + 1] = *(const float4*)(p + 4);
        }
    };
    auto convW = [&](int buf) {
#pragma unroll
        for (int m = 0; m < 4; ++m) {
            union { float4 f4[2]; u32 w[8]; } in;
            in.f4[0] = wv[buf][2 * m];
            in.f4[1] = wv[buf][2 * m + 1];
            union { u32 w[4]; bf16x8 v; } H, L;
#pragma unroll
            for (int j = 0; j < 4; ++j) {
                const u32 u0 = in.w[2 * j], u1 = in.w[2 * j + 1];
                const float x0 = __builtin_bit_cast(float, u0);
                const float x1 = __builtin_bit_cast(float, u1);
                const float h0 = __builtin_bit_cast(float, u0 & 0xFFFF0000u);
                const float h1 = __builtin_bit_cast(float, u1 & 0xFFFF0000u);
                const u32 l0 = __builtin_bit_cast(u32, x0 - h0);
                const u32 l1 = __builtin_bit_cast(u32, x1 - h1);
                H.w[j] = (u0 >> 16) | (u1 & 0xFFFF0000u);
                L.w[j] = (l0 >> 16) | (l1 & 0xFFFF0000u);
            }
            wh[m] = H.v;
            wl[m] = L.v;
        }
    };

    // ---- stage 1: no LDS, no barriers ----
    loadY(0, 0); loadW4(0, 0); loadY(1, 32); loadW4(1, 32);
#pragma unroll
    for (int it = 0; it < 8; ++it) {
        const int cur = it & 1;
        convW(cur);
        __builtin_amdgcn_s_setprio(1);
#pragma unroll
        for (int n = 0; n < 4; ++n) {
            union { u32 w[4]; bf16x8 v; } BH, BL;
#pragma unroll
            for (int j = 0; j < 4; ++j) {
                const u32 y0 = yf[cur][n][2 * j], y1 = yf[cur][n][2 * j + 1];
                BH.w[j] = (y0 & 0xFFFFu) | (y1 << 16);
                BL.w[j] = (y0 >> 16)     | (y1 & 0xFFFF0000u);
            }
#pragma unroll
            for (int m = 0; m < 4; ++m)
                acc1[m][n] = __builtin_amdgcn_mfma_f32_16x16x32_bf16(wh[m], BH.v, acc1[m][n], 0, 0, 0);
#pragma unroll
            for (int m = 0; m < 4; ++m)
                acc1[m][n] = __builtin_amdgcn_mfma_f32_16x16x32_bf16(wh[m], BL.v, acc1[m][n], 0, 0, 0);
#pragma unroll
            for (int m = 0; m < 4; ++m)
                acc1[m][n] = __builtin_amdgcn_mfma_f32_16x16x32_bf16(wl[m], BH.v, acc1[m][n], 0, 0, 0);
        }
        __builtin_amdgcn_s_setprio(0);
        if (it + 2 < 8) { loadY(cur, 32 * it + 64); loadW4(cur, 32 * it + 64); }
    }

    // ---- stage 2: K-windows of 64 (window kw = acc1[kw]) ----
    f32x4 acc2[4][4];
#pragma unroll
    for (int m = 0; m < 4; ++m)
#pragma unroll
        for (int n = 0; n < 4; ++n)
            acc2[m][n] = (f32x4){0.f, 0.f, 0.f, 0.f};

    float b4v[4][4];
#pragma unroll
    for (int kw = 0; kw < 4; ++kw)
#pragma unroll
        for (int r = 0; r < 4; ++r)
            b4v[kw][r] = b4[(size_t)parent * 256 + ocbase + kw * 16 + lk * 4 + r];

    loadW5(0, 0); loadW5(1, 1);

#pragma unroll
    for (int kw = 0; kw < 4; ++kw) {
        // write window kw: k_global = i*4 + par, i = kw*16 + lk*4 + r
#pragma unroll
        for (int n = 0; n < 4; ++n) {
            const int colg = wave * 64 + n * 16 + l16;
            const int b_ = colg >> 2, par = colg & 3;
#pragma unroll
            for (int r = 0; r < 4; ++r) {
                const float v = fmaxf(acc1[kw][n][r] + b4v[kw][r], 0.f);
                const int k_ = lk * 16 + r * 4 + par;
                const u32 uv = __builtin_bit_cast(u32, v);
                const float hi = __builtin_bit_cast(float, uv & 0xFFFF0000u);
                Whi_w[b_ * LDW + k_] = (u16)(uv >> 16);
                Wlo_w[b_ * LDW + k_] = (u16)(__builtin_bit_cast(u32, v - hi) >> 16);
            }
        }
        bar_lds();                       // window visible (global loads in flight)
#pragma unroll
        for (int kc = 0; kc < 2; ++kc) {
            const int t = kw * 2 + kc;
            const int cur = t & 1;
            convW(cur);                  // waits on W5 chunk t (issued 2 ago)
            __builtin_amdgcn_s_setprio(1);
#pragma unroll
            for (int n = 0; n < 4; ++n) {
                const int b_ = n * 16 + l16;
                const bf16x8 bhi = *(const bf16x8*)&Whi_w[b_ * LDW + kc * 32 + 8 * lk];
                const bf16x8 blo = *(const bf16x8*)&Wlo_w[b_ * LDW + kc * 32 + 8 * lk];
#pragma unroll
                for (int m = 0; m < 4; ++m)
                    acc2[m][n] = __builtin_amdgcn_mfma_f32_16x16x32_bf16(wh[m], bhi, acc2[m][n], 0, 0, 0);
#pragma unroll
                for (int m = 0; m < 4; ++m)
                    acc2[m][n] = __builtin_amdgcn_mfma_f32_16x16x32_bf16(wh[m], blo, acc2[m][n], 0, 0, 0);
#pragma unroll
                for (int m = 0; m < 4; ++m)
                    acc2[m][n] = __builtin_amdgcn_mfma_f32_16x16x32_bf16(wl[m], bhi, acc2[m][n], 0, 0, 0);
            }
            __builtin_amdgcn_s_setprio(0);
            if (t + 2 < 8) loadW5(cur, t + 2);
        }
        bar_lds();                       // reads of window kw done before next write
    }

    // ---- fused final: per-wave child block, within-wave reduce over channels ----
    const int fy = 2 * cy + (wave >> 1), fx = 2 * cx + (wave & 1);
    const int blk = fy * 64 + fx;
    float wf0v[4][4], wf2v[4][4], biv[4][4];
#pragma unroll
    for (int m = 0; m < 4; ++m)
#pragma unroll
        for (int r = 0; r < 4; ++r) {
            const int cch = m * 16 + lk * 4 + r;
            wf0v[m][r] = wf[(size_t)blk * 256 + cch];
            wf2v[m][r] = wf[(size_t)blk * 256 + 128 + cch];
            biv[m][r]  = b5[(size_t)bid5 * 256 + wave * 64 + cch];
        }
    const float bf0 = bff[blk * 4 + 0], bf2 = bff[blk * 4 + 2];
#pragma unroll
    for (int n = 0; n < 4; ++n) {
        float a0 = 0.f, a2 = 0.f;
#pragma unroll
        for (int m = 0; m < 4; ++m)
#pragma unroll
            for (int r = 0; r < 4; ++r) {
                const float y = fmaxf(acc2[m][n][r] + biv[m][r], 0.f);
                a0 = fmaf(y, wf0v[m][r], a0);
                a2 = fmaf(y, wf2v[m][r], a2);
            }
        a0 += __shfl_xor(a0, 16); a0 += __shfl_xor(a0, 32);
        a2 += __shfl_xor(a2, 16); a2 += __shfl_xor(a2, 32);
        if (lk == n) {
            const float o0 = fmaxf(a0 + bf0, 0.f);
            const float o2 = fmaxf(a2 + bf2, 0.f);
            out[(size_t)(n * 16 + l16) * 4096 + blk] = (o0 - o2) * (1.0f / 4096.0f);
        }
    }
}

extern "C" void kernel_launch(void* const* d_in, const int* in_sizes, int n_in,
                              void* d_out, int out_size, void* d_ws, size_t ws_size,
                              hipStream_t stream) {
    (void)in_sizes; (void)n_in; (void)out_size; (void)ws_size;

    const float* xr = (const float*)d_in[0];
    const float* xi = (const float*)d_in[1];
    const float* w0 = (const float*)d_in[2];
    const float* b0 = (const float*)d_in[3];
    const float* wrec[5] = { (const float*)d_in[4],  (const float*)d_in[6],
                             (const float*)d_in[8],  (const float*)d_in[10],
                             (const float*)d_in[12] };
    const float* brec[5] = { (const float*)d_in[5],  (const float*)d_in[7],
                             (const float*)d_in[9],  (const float*)d_in[11],
                             (const float*)d_in[13] };
    const float* wf = (const float*)d_in[14];
    const float* bf = (const float*)d_in[15];
    float* out = (float*)d_out;

    u32* bufA = (u32*)d_ws;
    u32* bufB = bufA + (size_t)PLANE;

    layer0_kernel<<<dim3(256, 2), 256, 0, stream>>>(xr, xi, w0, b0, bufA);

    // layer 1: G=2,  S2=16, Nb=16384 (NT=64 -> 256 n-tiles)
    rec_mfma_kernel<64><<<dim3(256, 1, 4), 256, 0, stream>>>(
        bufA, wrec[0], brec[0], bufB, 1, 4);
    // layer 2: G=4,  S2=8,  Nb=4096 (NT=64 -> 64 n-tiles)
    rec_mfma_kernel<64><<<dim3(64, 1, 16), 256, 0, stream>>>(
        bufB, wrec[1], brec[1], bufA, 2, 3);
    // layer 3: G=8,  S2=4,  Nb=1024 (NT=64 -> 16 n-tiles)
    rec_mfma_kernel<64><<<dim3(16, 1, 64), 256, 0, stream>>>(
        bufA, wrec[2], brec[2], bufB, 3, 2);
    // layers 4+5+final fused: one wg per L5 block
    rec45_final_kernel<<<1024, 256, 0, stream>>>(
        bufB, wrec[3], brec[3], wrec[4], brec[4], wf, bf, out);
}

// Round 15
// 260.572 us; speedup vs baseline: 1.1862x; 1.1862x over previous
//
#include <hip/hip_runtime.h>
#include <cstddef>

// ButterFlyNet2D IDFT forward. Split-bf16 MFMA (3-pass: Whi*Yhi + Whi*Ylo + Wlo*Yhi).
// Activations: ONE u32 per element = packed (hi bf16 | lo bf16<<16).
//   Plane layout A[gy][gx][i][k][l][b][p][q] -> per block contiguous Y[256][Nb].
// R15 = exact revert to R13 (best: 260.8 us). R14's NT=64/occupancy-3 theory
// was refuted (+19%); this locks the best-measured variant as final state.
// Pipeline: L0 -> rec1(NT=128) -> rec2 -> rec3 -> fused L4+L5+final.
// All packs use truncation-split (hi = bit-trunc, lo = trunc of exact
// remainder), proven precision-safe (absmax 4.8e-7 vs 2.6e-6 threshold).

typedef unsigned int  u32;
typedef unsigned short u16;
typedef __attribute__((ext_vector_type(8))) short bf16x8;
typedef __attribute__((ext_vector_type(4))) float f32x4;

#define PLANE 16777216   // elements per activation buffer

__device__ inline float bf16_to_f(u16 h) {
    u32 u = ((u32)h) << 16;
    return __builtin_bit_cast(float, u);
}
// Truncation-split pack: hi = bit-trunc(x) (top16), lo = trunc_bf16(x - hi).
// x - hi is exact in f32; |x - (hi+lo)| <= 2^-16 |x|. ~4 VALU ops.
__device__ inline u32 pack_trunc(float v) {
    const u32 u = __builtin_bit_cast(u32, v);
    const float hi = __builtin_bit_cast(float, u & 0xFFFF0000u);
    const u32 lo = __builtin_bit_cast(u32, v - hi);
    return (u >> 16) | (lo & 0xFFFF0000u);
}
// LDS-only barrier: drains ds ops, leaves global loads (vmcnt) in flight.
__device__ inline void bar_lds() {
    asm volatile("s_waitcnt lgkmcnt(0)\n\ts_barrier" ::: "memory");
}

// ---------------- Layer 0: x read once, 128 outputs per thread ----------------
__global__ __launch_bounds__(256)
void layer0_kernel(const float* __restrict__ xr, const float* __restrict__ xi,
                   const float* __restrict__ w0, const float* __restrict__ b0,
                   u32* __restrict__ A1) {
    __shared__ float w0s[128][16];
    __shared__ float b0s[128];
    const int og  = blockIdx.y;             // 0/1: o = og*128 + j
    const int tid = threadIdx.x;
    {
        const int row = tid >> 1, half = tid & 1;
        const float4 wa = *(const float4*)(w0 + (og * 128 + row) * 16 + half * 8);
        const float4 wb = *(const float4*)(w0 + (og * 128 + row) * 16 + half * 8 + 4);
        *(float4*)&w0s[row][half * 8]     = wa;
        *(float4*)&w0s[row][half * 8 + 4] = wb;
        if (tid < 128) b0s[tid] = b0[og * 128 + tid];
    }
    __syncthreads();

    const int n = blockIdx.x * 256 + tid;   // output pixel: b*1024 + p*32 + q
    const int b = n >> 10, p = (n >> 5) & 31, q = n & 31;
    float xs[16];
#pragma unroll
    for (int k = 0; k < 2; ++k) {
        const float2 vr = *(const float2*)(xr + b * 4096 + (2 * p + k) * 64 + 2 * q);
        const float2 vi = *(const float2*)(xi + b * 4096 + (2 * p + k) * 64 + 2 * q);
        xs[0  + k * 2 + 0] = fmaxf(vr.x, 0.f);  xs[0  + k * 2 + 1] = fmaxf(vr.y, 0.f);
        xs[4  + k * 2 + 0] = fmaxf(vi.x, 0.f);  xs[4  + k * 2 + 1] = fmaxf(vi.y, 0.f);
        xs[8  + k * 2 + 0] = fmaxf(-vr.x, 0.f); xs[8  + k * 2 + 1] = fmaxf(-vr.y, 0.f);
        xs[12 + k * 2 + 0] = fmaxf(-vi.x, 0.f); xs[12 + k * 2 + 1] = fmaxf(-vi.y, 0.f);
    }
    const int kp = p & 1, lp = q & 1, pp = p >> 1, qp = q >> 1;
    const size_t pixoff = (size_t)(b * 256 + pp * 16 + qp);
#pragma unroll
    for (int j = 0; j < 128; ++j) {
        float acc = b0s[j];
#pragma unroll
        for (int e = 0; e < 16; ++e) acc = fmaf(xs[e], w0s[j][e], acc);
        acc = fmaxf(acc, 0.f);
        const int o = og * 128 + j;
        const int gy = o >> 7, gx = (o >> 6) & 1, c = o & 63;
        const size_t flat = (size_t)((((gy * 2 + gx) * 64 + c) * 2 + kp) * 2 + lp) * (64 * 256)
                          + pixoff;
        A1[flat] = pack_trunc(acc);
    }
}

// ------- Recursion layers 1..3 : split-bf16 MFMA, W f32 direct + trunc-split -------
template<int NT>
__global__ __launch_bounds__(256, 2)
void rec_mfma_kernel(const u32* __restrict__ Yg, const float* __restrict__ Wf,
                     const float* __restrict__ bias, u32* __restrict__ Aout,
                     const int lgG, const int lgS2) {
    constexpr int NF  = NT / 16;
    constexpr int LD  = 40;
    constexpr int NCP = NT / 2;
    constexpr int RPT = 32 / (256 / NCP);

    __shared__ u16 Yhi_s[NT * LD];
    __shared__ u16 Ylo_s[NT * LD];

    const int G  = 1 << lgG;
    const int S2 = 1 << lgS2;
    const int Nb = 64 << (2 * lgS2);

    // XCD-chunked swizzle: keep all n-tiles of a block on one XCD (W L2 reuse)
    int bid, nt;
    const int nBid = G * G, NTILES = gridDim.x;
    if (nBid >= 8) {
        const int h = blockIdx.z * NTILES + blockIdx.x;
        const int xcd = h & 7, j = h >> 3, per = nBid >> 3;
        bid = xcd * per + j / NTILES;
        nt  = j % NTILES;
    } else { bid = blockIdx.z; nt = blockIdx.x; }

    const size_t wbase = (size_t)bid * 65536;
    const u32* Yblk = Yg + (size_t)bid * 256 * (size_t)Nb + (size_t)nt * NT;

    const int tid = threadIdx.x, wave = tid >> 6, lane = tid & 63;
    const int l16 = lane & 15, lk = lane >> 4;
    const int cp = tid % NCP, rg = tid / NCP;
    const int col0 = cp * 2, trow = rg * RPT;

    f32x4 acc[4][NF];
#pragma unroll
    for (int m = 0; m < 4; ++m)
#pragma unroll
        for (int n = 0; n < NF; ++n)
            acc[m][n] = (f32x4){0.f, 0.f, 0.f, 0.f};

    uint2  yreg[2][RPT];
    float4 wv[8];
    bf16x8 wh[4], wl[4];
    u32 yhw[2][RPT / 2], ylw[2][RPT / 2];

    auto loadY = [&](int ybuf, int k0) {
#pragma unroll
        for (int r = 0; r < RPT; ++r)
            yreg[ybuf][r] = *(const uint2*)(Yblk + (size_t)(k0 + trow + r) * Nb + col0);
    };
    auto loadWf32 = [&](int k0) {
#pragma unroll
        for (int m = 0; m < 4; ++m) {
            const float* p = Wf + wbase + (size_t)(wave * 64 + m * 16 + l16) * 256 + k0 + lk * 8;
            wv[2 * m]     = *(const float4*)p;
            wv[2 * m + 1] = *(const float4*)(p + 4);
        }
    };
    auto convW = [&]() {
#pragma unroll
        for (int m = 0; m < 4; ++m) {
            union { float4 f4[2]; u32 w[8]; } in;
            in.f4[0] = wv[2 * m];
            in.f4[1] = wv[2 * m + 1];
            union { u32 w[4]; bf16x8 v; } H, L;
#pragma unroll
            for (int j = 0; j < 4; ++j) {
                const u32 u0 = in.w[2 * j], u1 = in.w[2 * j + 1];
                const float x0 = __builtin_bit_cast(float, u0);
                const float x1 = __builtin_bit_cast(float, u1);
                const float h0 = __builtin_bit_cast(float, u0 & 0xFFFF0000u);
                const float h1 = __builtin_bit_cast(float, u1 & 0xFFFF0000u);
                const u32 l0 = __builtin_bit_cast(u32, x0 - h0);
                const u32 l1 = __builtin_bit_cast(u32, x1 - h1);
                H.w[j] = (u0 >> 16) | (u1 & 0xFFFF0000u);
                L.w[j] = (l0 >> 16) | (l1 & 0xFFFF0000u);
            }
            wh[m] = H.v;
            wl[m] = L.v;
        }
    };
    auto prepY = [&](int ybuf) {
#pragma unroll
        for (int c = 0; c < 2; ++c)
#pragma unroll
            for (int j2 = 0; j2 < RPT / 2; ++j2) {
                const u32 a = c ? yreg[ybuf][2 * j2].y     : yreg[ybuf][2 * j2].x;
                const u32 b = c ? yreg[ybuf][2 * j2 + 1].y : yreg[ybuf][2 * j2 + 1].x;
                yhw[c][j2] = (a & 0xFFFFu) | (b << 16);
                ylw[c][j2] = (a >> 16)     | (b & 0xFFFF0000u);
            }
    };
    auto stageY = [&]() {
#pragma unroll
        for (int c = 0; c < 2; ++c) {
            if constexpr (RPT == 8) {
                *(uint4*)&Yhi_s[(col0 + c) * LD + trow] = make_uint4(yhw[c][0], yhw[c][1], yhw[c][2], yhw[c][3]);
                *(uint4*)&Ylo_s[(col0 + c) * LD + trow] = make_uint4(ylw[c][0], ylw[c][1], ylw[c][2], ylw[c][3]);
            } else {
                *(uint2*)&Yhi_s[(col0 + c) * LD + trow] = make_uint2(yhw[c][0], yhw[c][1]);
                *(uint2*)&Ylo_s[(col0 + c) * LD + trow] = make_uint2(ylw[c][0], ylw[c][1]);
            }
        }
    };

    loadY(0, 0); loadY(1, 32);

#pragma unroll
    for (int it = 0; it < 8; ++it) {
        const int k0 = it * 32;
        const int cur = it & 1;
        loadWf32(k0);            // in flight across barriers (no vmcnt drain)
        prepY(cur);              // waits on yreg[cur] (issued 2 iters ago)
        bar_lds();               // prev MFMA ds_reads done; LDS reusable
        stageY();
        bar_lds();               // Y tile visible
        if (it + 2 < 8) loadY(cur, k0 + 64);
        convW();                 // waits on wv (issued before the barriers)
        __builtin_amdgcn_s_setprio(1);
#pragma unroll
        for (int n = 0; n < NF; ++n) {
            const int ccol = n * 16 + l16;
            const bf16x8 bhi = *(const bf16x8*)&Yhi_s[ccol * LD + 8 * lk];
            const bf16x8 blo = *(const bf16x8*)&Ylo_s[ccol * LD + 8 * lk];
#pragma unroll
            for (int m = 0; m < 4; ++m)
                acc[m][n] = __builtin_amdgcn_mfma_f32_16x16x32_bf16(wh[m], bhi, acc[m][n], 0, 0, 0);
#pragma unroll
            for (int m = 0; m < 4; ++m)
                acc[m][n] = __builtin_amdgcn_mfma_f32_16x16x32_bf16(wh[m], blo, acc[m][n], 0, 0, 0);
#pragma unroll
            for (int m = 0; m < 4; ++m)
                acc[m][n] = __builtin_amdgcn_mfma_f32_16x16x32_bf16(wl[m], bhi, acc[m][n], 0, 0, 0);
        }
        __builtin_amdgcn_s_setprio(0);
    }

    // ---- epilogue: bias + relu + packed scatter to child blocks ----
    const int gy = bid >> lgG, gx = bid & (G - 1);
    const int NS2 = S2 >> 1;
#pragma unroll
    for (int m = 0; m < 4; ++m) {
#pragma unroll
        for (int r = 0; r < 4; ++r) {
            const int oc = wave * 64 + m * 16 + lk * 4 + r;   // C/D: row=(lane>>4)*4+reg
            const float bi = bias[(size_t)bid * 256 + oc];
            const int yl = oc >> 7, xl = (oc >> 6) & 1, cch = oc & 63;
            const int cy = 2 * gy + yl, cx = 2 * gx + xl;
            const size_t base = (size_t)((cy * (2 * G) + cx) * 64 + cch);
#pragma unroll
            for (int n = 0; n < NF; ++n) {
                const float v = fmaxf(acc[m][n][r] + bi, 0.f);
                const int ng = nt * NT + n * 16 + l16;        // C/D: col=lane&15
                const int b   = ng >> (2 * lgS2);
                const int rem = ng & ((1 << (2 * lgS2)) - 1);
                const int p = rem >> lgS2, q = rem & (S2 - 1);
                const size_t flat = ((base * 2 + (p & 1)) * 2 + (q & 1)) * (size_t)(64 * NS2 * NS2)
                                  + (size_t)(b * NS2 * NS2 + (p >> 1) * NS2 + (q >> 1));
                Aout[flat] = pack_trunc(v);
            }
        }
    }
}

// ---------------- Fused L4 + L5 + final ----------------
__global__ __launch_bounds__(256, 2)
void rec45_final_kernel(const u32* __restrict__ Yg, const float* __restrict__ W4,
                        const float* __restrict__ b4, const float* __restrict__ W5,
                        const float* __restrict__ b5, const float* __restrict__ wf,
                        const float* __restrict__ bff, float* __restrict__ out) {
    constexpr int LDW = 72;                 // window row stride (u16)
    __shared__ u16 Whi_w[64 * LDW];
    __shared__ u16 Wlo_w[64 * LDW];

    const int h = blockIdx.x;
    const int parent = ((h >> 5) << 3) | (h & 7);   // 0..255 = pgy*16+pgx
    const int child  = (h >> 3) & 3;
    const int pgy = parent >> 4, pgx = parent & 15;
    const int cy = 2 * pgy + (child >> 1), cx = 2 * pgx + (child & 1);
    const int bid5 = cy * 32 + cx;
    const int ocbase = child * 64;

    const u32* Yblk  = Yg + (size_t)parent * 65536;
    const float* W4s = W4 + (size_t)parent * 65536 + (size_t)ocbase * 256;
    const float* W5b = W5 + (size_t)bid5 * 65536;

    const int tid = threadIdx.x, wave = tid >> 6, lane = tid & 63;
    const int l16 = lane & 15, lk = lane >> 4;

    f32x4 acc1[4][4];
#pragma unroll
    for (int m = 0; m < 4; ++m)
#pragma unroll
        for (int n = 0; n < 4; ++n)
            acc1[m][n] = (f32x4){0.f, 0.f, 0.f, 0.f};

    u32    yf[2][4][8];
    float4 wv[2][8];
    bf16x8 wh[4], wl[4];

    auto loadY = [&](int buf, int k0) {
#pragma unroll
        for (int n = 0; n < 4; ++n)
#pragma unroll
            for (int j = 0; j < 8; ++j)
                yf[buf][n][j] = Yblk[(size_t)(k0 + 8 * lk + j) * 256 + wave * 64 + n * 16 + l16];
    };
    auto loadW4 = [&](int buf, int k0) {
#pragma unroll
        for (int m = 0; m < 4; ++m) {
            const float* p = W4s + (size_t)(m * 16 + l16) * 256 + k0 + lk * 8;
            wv[buf][2 * m]     = *(const float4*)p;
            wv[buf][2 * m + 1] = *(const float4*)(p + 4);
        }
    };
    auto loadW5 = [&](int buf, int t) {
#pragma unroll
        for (int m = 0; m < 4; ++m) {
            const float* p = W5b + (size_t)(wave * 64 + m * 16 + l16) * 256 + t * 32 + lk * 8;
            wv[buf][2 * m]     = *(const float4*)p;
            wv[buf][2 * m + 1] = *(const float4*)(p + 4);
        }
    };
    auto convW = [&](int buf) {
#pragma unroll
        for (int m = 0; m < 4; ++m) {
            union { float4 f4[2]; u32 w[8]; } in;
            in.f4[0] = wv[buf][2 * m];
            in.f4[1] = wv[buf][2 * m + 1];
            union { u32 w[4]; bf16x8 v; } H, L;
#pragma unroll
            for (int j = 0; j < 4; ++j) {
                const u32 u0 = in.w[2 * j], u1 = in.w[2 * j + 1];
                const float x0 = __builtin_bit_cast(float, u0);
                const float x1 = __builtin_bit_cast(float, u1);
                const float h0 = __builtin_bit_cast(float, u0 & 0xFFFF0000u);
                const float h1 = __builtin_bit_cast(float, u1 & 0xFFFF0000u);
                const u32 l0 = __builtin_bit_cast(u32, x0 - h0);
                const u32 l1 = __builtin_bit_cast(u32, x1 - h1);
                H.w[j] = (u0 >> 16) | (u1 & 0xFFFF0000u);
                L.w[j] = (l0 >> 16) | (l1 & 0xFFFF0000u);
            }
            wh[m] = H.v;
            wl[m] = L.v;
        }
    };

    // ---- stage 1: no LDS, no barriers ----
    loadY(0, 0); loadW4(0, 0); loadY(1, 32); loadW4(1, 32);
#pragma unroll
    for (int it = 0; it < 8; ++it) {
        const int cur = it & 1;
        convW(cur);
        __builtin_amdgcn_s_setprio(1);
#pragma unroll
        for (int n = 0; n < 4; ++n) {
            union { u32 w[4]; bf16x8 v; } BH, BL;
#pragma unroll
            for (int j = 0; j < 4; ++j) {
                const u32 y0 = yf[cur][n][2 * j], y1 = yf[cur][n][2 * j + 1];
                BH.w[j] = (y0 & 0xFFFFu) | (y1 << 16);
                BL.w[j] = (y0 >> 16)     | (y1 & 0xFFFF0000u);
            }
#pragma unroll
            for (int m = 0; m < 4; ++m)
                acc1[m][n] = __builtin_amdgcn_mfma_f32_16x16x32_bf16(wh[m], BH.v, acc1[m][n], 0, 0, 0);
#pragma unroll
            for (int m = 0; m < 4; ++m)
                acc1[m][n] = __builtin_amdgcn_mfma_f32_16x16x32_bf16(wh[m], BL.v, acc1[m][n], 0, 0, 0);
#pragma unroll
            for (int m = 0; m < 4; ++m)
                acc1[m][n] = __builtin_amdgcn_mfma_f32_16x16x32_bf16(wl[m], BH.v, acc1[m][n], 0, 0, 0);
        }
        __builtin_amdgcn_s_setprio(0);
        if (it + 2 < 8) { loadY(cur, 32 * it + 64); loadW4(cur, 32 * it + 64); }
    }

    // ---- stage 2: K-windows of 64 (window kw = acc1[kw]) ----
    f32x4 acc2[4][4];
#pragma unroll
    for (int m = 0; m < 4; ++m)
#pragma unroll
        for (int n = 0; n < 4; ++n)
            acc2[m][n] = (f32x4){0.f, 0.f, 0.f, 0.f};

    float b4v[4][4];
#pragma unroll
    for (int kw = 0; kw < 4; ++kw)
#pragma unroll
        for (int r = 0; r < 4; ++r)
            b4v[kw][r] = b4[(size_t)parent * 256 + ocbase + kw * 16 + lk * 4 + r];

    loadW5(0, 0); loadW5(1, 1);

#pragma unroll
    for (int kw = 0; kw < 4; ++kw) {
        // write window kw: k_global = i*4 + par, i = kw*16 + lk*4 + r
#pragma unroll
        for (int n = 0; n < 4; ++n) {
            const int colg = wave * 64 + n * 16 + l16;
            const int b_ = colg >> 2, par = colg & 3;
#pragma unroll
            for (int r = 0; r < 4; ++r) {
                const float v = fmaxf(acc1[kw][n][r] + b4v[kw][r], 0.f);
                const int k_ = lk * 16 + r * 4 + par;
                const u32 uv = __builtin_bit_cast(u32, v);
                const float hi = __builtin_bit_cast(float, uv & 0xFFFF0000u);
                Whi_w[b_ * LDW + k_] = (u16)(uv >> 16);
                Wlo_w[b_ * LDW + k_] = (u16)(__builtin_bit_cast(u32, v - hi) >> 16);
            }
        }
        bar_lds();                       // window visible (global loads in flight)
#pragma unroll
        for (int kc = 0; kc < 2; ++kc) {
            const int t = kw * 2 + kc;
            const int cur = t & 1;
            convW(cur);                  // waits on W5 chunk t (issued 2 ago)
            __builtin_amdgcn_s_setprio(1);
#pragma unroll
            for (int n = 0; n < 4; ++n) {
                const int b_ = n * 16 + l16;
                const bf16x8 bhi = *(const bf16x8*)&Whi_w[b_ * LDW + kc * 32 + 8 * lk];
                const bf16x8 blo = *(const bf16x8*)&Wlo_w[b_ * LDW + kc * 32 + 8 * lk];
#pragma unroll
                for (int m = 0; m < 4; ++m)
                    acc2[m][n] = __builtin_amdgcn_mfma_f32_16x16x32_bf16(wh[m], bhi, acc2[m][n], 0, 0, 0);
#pragma unroll
                for (int m = 0; m < 4; ++m)
                    acc2[m][n] = __builtin_amdgcn_mfma_f32_16x16x32_bf16(wh[m], blo, acc2[m][n], 0, 0, 0);
#pragma unroll
                for (int m = 0; m < 4; ++m)
                    acc2[m][n] = __builtin_amdgcn_mfma_f32_16x16x32_bf16(wl[m], bhi, acc2[m][n], 0, 0, 0);
            }
            __builtin_amdgcn_s_setprio(0);
            if (t + 2 < 8) loadW5(cur, t + 2);
        }
        bar_lds();                       // reads of window kw done before next write
    }

    // ---- fused final: per-wave child block, within-wave reduce over channels ----
    const int fy = 2 * cy + (wave >> 1), fx = 2 * cx + (wave & 1);
    const int blk = fy * 64 + fx;
    float wf0v[4][4], wf2v[4][4], biv[4][4];
#pragma unroll
    for (int m = 0; m < 4; ++m)
#pragma unroll
        for (int r = 0; r < 4; ++r) {
            const int cch = m * 16 + lk * 4 + r;
            wf0v[m][r] = wf[(size_t)blk * 256 + cch];
            wf2v[m][r] = wf[(size_t)blk * 256 + 128 + cch];
            biv[m][r]  = b5[(size_t)bid5 * 256 + wave * 64 + cch];
        }
    const float bf0 = bff[blk * 4 + 0], bf2 = bff[blk * 4 + 2];
#pragma unroll
    for (int n = 0; n < 4; ++n) {
        float a0 = 0.f, a2 = 0.f;
#pragma unroll
        for (int m = 0; m < 4; ++m)
#pragma unroll
            for (int r = 0; r < 4; ++r) {
                const float y = fmaxf(acc2[m][n][r] + biv[m][r], 0.f);
                a0 = fmaf(y, wf0v[m][r], a0);
                a2 = fmaf(y, wf2v[m][r], a2);
            }
        a0 += __shfl_xor(a0, 16); a0 += __shfl_xor(a0, 32);
        a2 += __shfl_xor(a2, 16); a2 += __shfl_xor(a2, 32);
        if (lk == n) {
            const float o0 = fmaxf(a0 + bf0, 0.f);
            const float o2 = fmaxf(a2 + bf2, 0.f);
            out[(size_t)(n * 16 + l16) * 4096 + blk] = (o0 - o2) * (1.0f / 4096.0f);
        }
    }
}

extern "C" void kernel_launch(void* const* d_in, const int* in_sizes, int n_in,
                              void* d_out, int out_size, void* d_ws, size_t ws_size,
                              hipStream_t stream) {
    (void)in_sizes; (void)n_in; (void)out_size; (void)ws_size;

    const float* xr = (const float*)d_in[0];
    const float* xi = (const float*)d_in[1];
    const float* w0 = (const float*)d_in[2];
    const float* b0 = (const float*)d_in[3];
    const float* wrec[5] = { (const float*)d_in[4],  (const float*)d_in[6],
                             (const float*)d_in[8],  (const float*)d_in[10],
                             (const float*)d_in[12] };
    const float* brec[5] = { (const float*)d_in[5],  (const float*)d_in[7],
                             (const float*)d_in[9],  (const float*)d_in[11],
                             (const float*)d_in[13] };
    const float* wf = (const float*)d_in[14];
    const float* bf = (const float*)d_in[15];
    float* out = (float*)d_out;

    u32* bufA = (u32*)d_ws;
    u32* bufB = bufA + (size_t)PLANE;

    layer0_kernel<<<dim3(256, 2), 256, 0, stream>>>(xr, xi, w0, b0, bufA);

    // layer 1: G=2,  S2=16, Nb=16384
    rec_mfma_kernel<128><<<dim3(128, 1, 4), 256, 0, stream>>>(
        bufA, wrec[0], brec[0], bufB, 1, 4);
    // layer 2: G=4,  S2=8,  Nb=4096
    rec_mfma_kernel<128><<<dim3(32, 1, 16), 256, 0, stream>>>(
        bufB, wrec[1], brec[1], bufA, 2, 3);
    // layer 3: G=8,  S2=4,  Nb=1024
    rec_mfma_kernel<128><<<dim3(8, 1, 64), 256, 0, stream>>>(
        bufA, wrec[2], brec[2], bufB, 3, 2);
    // layers 4+5+final fused: one wg per L5 block
    rec45_final_kernel<<<1024, 256, 0, stream>>>(
        bufB, wrec[3], brec[3], wrec[4], brec[4], wf, bf, out);
}